// Round 1
// baseline (728.338 us; speedup 1.0000x reference)
//
#include <hip/hip_runtime.h>

#define S_LEN 256
#define B_SZ  512
#define T_TAGS 128
#define TP2   130
#define PAD_I (-1)

// ---------------- Forward (log-partition) kernel ----------------
// One block per batch row b. 128 threads (2 waves); thread j owns output tag j.
// E columns kept in registers (128 VGPRs/thread). P broadcast via LDS.
__global__ __launch_bounds__(128) void fwd_kernel(
    const float* __restrict__ em,     // (S,B,T)
    const float* __restrict__ trans,  // (T+2,T+2)
    const int*   __restrict__ tags,   // (S,B)
    float* __restrict__ denom_out)    // (B)
{
    const int b = blockIdx.x;
    const int j = threadIdx.x;        // 0..127
    const int w = j >> 6;             // wave id 0/1

    // E[i][j] = exp(trans_tt[i][j]) into registers (column j), fully unrolled.
    float er[T_TAGS];
    #pragma unroll
    for (int i = 0; i < T_TAGS; ++i)
        er[i] = __expf(trans[i * TP2 + j]);

    // lp init: trans[start_tag=T][j] + emissions[0,b,j]
    float lp = trans[T_TAGS * TP2 + j] + em[(size_t)b * T_TAGS + j];

    __shared__ float P[2][T_TAGS];
    __shared__ float wred[2][2];

    // initial max (for step 1): wave reduce then stash per-wave max.
    {
        float m = lp;
        #pragma unroll
        for (int off = 32; off > 0; off >>= 1)
            m = fmaxf(m, __shfl_xor(m, off));
        if ((j & 63) == 0) wred[1][w] = m;   // step s writes wred[(s+1)&1]; "init" is s=0
    }

    for (int s = 1; s < S_LEN; ++s) {
        const int buf = s & 1;
        // issue independent loads early
        const float e  = em[((size_t)s * B_SZ + b) * T_TAGS + j];
        const int   tg = tags[s * B_SZ + b];   // uniform per block

        __syncthreads();   // (A) wred[buf] ready; P[buf] free (reads were 2 steps ago)
        const float M = fmaxf(wred[buf][0], wred[buf][1]);
        P[buf][j] = __expf(lp - M);
        __syncthreads();   // (B) P[buf] ready

        float a0 = 0.f, a1 = 0.f, a2 = 0.f, a3 = 0.f;
        const float4* __restrict__ p4p = (const float4*)P[buf];
        #pragma unroll
        for (int ii = 0; ii < T_TAGS / 4; ++ii) {
            const float4 p4 = p4p[ii];              // broadcast read (same addr all lanes)
            a0 = fmaf(p4.x, er[ii * 4 + 0], a0);
            a1 = fmaf(p4.y, er[ii * 4 + 1], a1);
            a2 = fmaf(p4.z, er[ii * 4 + 2], a2);
            a3 = fmaf(p4.w, er[ii * 4 + 3], a3);
        }
        const float acc = (a0 + a1) + (a2 + a3);
        const float nlp = M + __logf(acc) + e;
        lp = (tg != PAD_I) ? nlp : lp;

        // max for next step
        float m2 = lp;
        #pragma unroll
        for (int off = 32; off > 0; off >>= 1)
            m2 = fmaxf(m2, __shfl_xor(m2, off));
        if ((j & 63) == 0) wred[(s + 1) & 1][w] = m2;
    }

    // denom = logsumexp_j( lp + trans[j][end_tag=T+1] )
    const float dv = lp + trans[j * TP2 + (T_TAGS + 1)];
    float mf = dv;
    #pragma unroll
    for (int off = 32; off > 0; off >>= 1)
        mf = fmaxf(mf, __shfl_xor(mf, off));
    if ((j & 63) == 0) wred[0][w] = mf;
    __syncthreads();
    mf = fmaxf(wred[0][0], wred[0][1]);
    float ex = __expf(dv - mf);
    #pragma unroll
    for (int off = 32; off > 0; off >>= 1)
        ex += __shfl_xor(ex, off);
    if ((j & 63) == 0) P[0][w] = ex;
    __syncthreads();
    if (j == 0)
        denom_out[b] = mf + __logf(P[0][0] + P[0][1]);
}

// ---------------- Numerator kernel ----------------
// One thread per batch row.
__global__ __launch_bounds__(256) void numer_kernel(
    const float* __restrict__ em,
    const float* __restrict__ trans,
    const int*   __restrict__ tags,
    float* __restrict__ llh_out)
{
    const int b = blockIdx.x * 256 + threadIdx.x;
    if (b >= B_SZ) return;

    int t0 = tags[b];
    int cnt = (t0 != PAD_I) ? 1 : 0;
    // JAX negative indexing wraps for transitions[start, tags[0]]
    const int t0w = (t0 < 0) ? t0 + TP2 : t0;
    float llh = trans[T_TAGS * TP2 + t0w];

    float emit_prev = em[(size_t)b * T_TAGS + ((t0 < 0) ? 0 : t0)]; // take_along_axis clips
    float mask_prev = (t0 != PAD_I) ? 1.f : 0.f;
    int prev = t0;

    for (int s = 1; s < S_LEN; ++s) {
        const int c  = tags[(size_t)s * B_SZ + b];
        const float ms = (c != PAD_I) ? 1.f : 0.f;
        llh += emit_prev * mask_prev;                      // emit[s-1]*mask[s-1], s-1<=S-2
        const int pw = (prev < 0) ? prev + TP2 : prev;
        const int cw = (c    < 0) ? c    + TP2 : c;
        llh += trans[pw * TP2 + cw] * ms;                  // trans[tags[s-1],tags[s]]*mask[s]
        cnt += (c != PAD_I) ? 1 : 0;
        emit_prev = em[((size_t)s * B_SZ + b) * T_TAGS + ((c < 0) ? 0 : c)];
        mask_prev = ms;
        prev = c;
    }

    int li = cnt - 1; if (li < 0) li = 0;
    const int lt  = tags[(size_t)li * B_SZ + b];
    const int ltw = (lt < 0) ? lt + TP2 : lt;
    llh += trans[ltw * TP2 + (T_TAGS + 1)];
    const float mlast = (tags[(size_t)(S_LEN - 1) * B_SZ + b] != PAD_I) ? 1.f : 0.f;
    llh += em[((size_t)(S_LEN - 1) * B_SZ + b) * T_TAGS + ((lt < 0) ? 0 : lt)] * mlast;

    llh_out[b] = llh;
}

// ---------------- Final mean reduce ----------------
__global__ __launch_bounds__(512) void reduce_kernel(
    const float* __restrict__ llh, const float* __restrict__ denom,
    float* __restrict__ out)
{
    const int t = threadIdx.x;
    float v = llh[t] - denom[t];
    #pragma unroll
    for (int off = 32; off > 0; off >>= 1)
        v += __shfl_xor(v, off);
    __shared__ float sred[8];
    if ((t & 63) == 0) sred[t >> 6] = v;
    __syncthreads();
    if (t == 0) {
        float s = 0.f;
        #pragma unroll
        for (int k = 0; k < 8; ++k) s += sred[k];
        out[0] = s * (1.f / (float)B_SZ);
    }
}

extern "C" void kernel_launch(void* const* d_in, const int* in_sizes, int n_in,
                              void* d_out, int out_size, void* d_ws, size_t ws_size,
                              hipStream_t stream) {
    const float* em    = (const float*)d_in[0];
    const float* trans = (const float*)d_in[1];
    const int*   tags  = (const int*)d_in[2];
    float* out   = (float*)d_out;
    float* llh   = (float*)d_ws;
    float* denom = llh + B_SZ;

    numer_kernel<<<2, 256, 0, stream>>>(em, trans, tags, llh);
    fwd_kernel<<<B_SZ, 128, 0, stream>>>(em, trans, tags, denom);
    reduce_kernel<<<1, 512, 0, stream>>>(llh, denom, out);
}

// Round 2
// 330.833 us; speedup vs baseline: 2.2015x; 2.2015x over previous
//
#include <hip/hip_runtime.h>

#define S_LEN 256
#define B_SZ  512
#define T_TAGS 128
#define TP2   130
#define PAD_I (-1)
#define NCHUNK 16
#define CH_LEN (S_LEN / NCHUNK)

// LDS-only barrier: drains LDS ops, leaves global loads in flight (no vmcnt(0)).
__device__ __forceinline__ void bar_lds() {
    asm volatile("s_waitcnt lgkmcnt(0)\n\ts_barrier" ::: "memory");
}

// ---------------- Forward (log-partition) kernel ----------------
// One block per batch row. 512 threads = 8 waves. thread (j = t&127, h = t>>7).
// Thread (j,h) holds E[i][j] for i in [32h, 32h+32) in 32 VGPRs.
// h==0 threads (waves 0-1) own the state lp[j]; all waves compute dot partials.
__global__ __launch_bounds__(512) void fwd_kernel(
    const float* __restrict__ em,     // (S,B,T)
    const float* __restrict__ trans,  // (T+2,T+2)
    const int*   __restrict__ tags,   // (S,B)
    float* __restrict__ denom_out)    // (B)
{
    const int b = blockIdx.x;
    const int t = threadIdx.x;
    const int j = t & (T_TAGS - 1);
    const int h = t >> 7;             // 0..3 (pairs of waves)

    float er[32];
    #pragma unroll
    for (int i = 0; i < 32; ++i)
        er[i] = __expf(trans[(32 * h + i) * TP2 + j]);

    __shared__ float P[2][T_TAGS];
    __shared__ float part[3][T_TAGS];
    __shared__ float wred[2][2];
    __shared__ float smA[8], smB[8];

    float lp = 0.f;
    if (h == 0)
        lp = trans[T_TAGS * TP2 + j] + em[(size_t)b * T_TAGS + j];

    // prime wred[0] and wred[1] with block-max of state0
    if (h == 0) {
        float m = lp;
        #pragma unroll
        for (int off = 32; off; off >>= 1)
            m = fmaxf(m, __shfl_xor(m, off));
        if ((j & 63) == 0) { wred[0][j >> 6] = m; wred[1][j >> 6] = m; }
    }
    bar_lds();

    float e_cur = (h == 0) ? em[((size_t)1 * B_SZ + b) * T_TAGS + j] : 0.f;

    for (int s = 1; s < S_LEN; ++s) {
        const int buf = s & 1;
        float e_next = 0.f;
        int tg = 0;
        float M = 0.f;
        if (h == 0) {
            if (s < S_LEN - 1)
                e_next = em[((size_t)(s + 1) * B_SZ + b) * T_TAGS + j];
            tg = tags[s * B_SZ + b];
            M = fmaxf(wred[buf][0], wred[buf][1]);
            P[buf][j] = __expf(lp - M);
        }
        bar_lds();   // B1: P[buf] visible

        // dot partial over i in [32h, 32h+32) — broadcast LDS reads
        const float4* __restrict__ p4 = (const float4*)&P[buf][32 * h];
        float a0 = 0.f, a1 = 0.f, a2 = 0.f, a3 = 0.f;
        #pragma unroll
        for (int ii = 0; ii < 8; ++ii) {
            const float4 p = p4[ii];
            a0 = fmaf(p.x, er[4 * ii + 0], a0);
            a1 = fmaf(p.y, er[4 * ii + 1], a1);
            a2 = fmaf(p.z, er[4 * ii + 2], a2);
            a3 = fmaf(p.w, er[4 * ii + 3], a3);
        }
        const float ph = (a0 + a1) + (a2 + a3);
        if (h) part[h - 1][j] = ph;

        // max chain on current state (overlaps dot); result used at iter s+2
        float mchain = lp;
        if (h == 0) {
            #pragma unroll
            for (int off = 32; off; off >>= 1)
                mchain = fmaxf(mchain, __shfl_xor(mchain, off));
        }
        bar_lds();   // B2: partials visible

        if (h == 0) {
            const float acc = ph + part[0][j] + part[1][j] + part[2][j];
            const float nlp = M + __logf(acc) + e_cur;
            lp = (tg != PAD_I) ? nlp : lp;
            if ((j & 63) == 0) wred[buf][j >> 6] = mchain;   // read at iter s+2
        }
        e_cur = e_next;
    }

    // epilogue: denom = logsumexp_j( lp + trans[j][end_tag] )
    float dv = (h == 0) ? (lp + trans[j * TP2 + (T_TAGS + 1)]) : -1e30f;
    float mf = dv;
    #pragma unroll
    for (int off = 32; off; off >>= 1)
        mf = fmaxf(mf, __shfl_xor(mf, off));
    if ((t & 63) == 0) smA[t >> 6] = mf;
    bar_lds();
    mf = fmaxf(smA[0], smA[1]);
    float ex = (h == 0) ? __expf(dv - mf) : 0.f;
    #pragma unroll
    for (int off = 32; off; off >>= 1)
        ex += __shfl_xor(ex, off);
    if ((t & 63) == 0) smB[t >> 6] = ex;
    bar_lds();
    if (t == 0)
        denom_out[b] = mf + __logf(smB[0] + smB[1]);
}

// ---------------- Numerator partials ----------------
// Block q handles s in [q*CH_LEN, (q+1)*CH_LEN); thread = batch row b (coalesced tags).
__global__ __launch_bounds__(512) void numer_part(
    const float* __restrict__ em,
    const float* __restrict__ trans,
    const int*   __restrict__ tags,
    float* __restrict__ pl, int* __restrict__ pc)
{
    const int b = threadIdx.x;
    const int q = blockIdx.x;
    const int s0 = q * CH_LEN;

    int tg[CH_LEN + 1];
    tg[0] = (s0 == 0) ? PAD_I : tags[(s0 - 1) * B_SZ + b];
    #pragma unroll
    for (int k = 0; k < CH_LEN; ++k)
        tg[k + 1] = tags[(s0 + k) * B_SZ + b];

    float acc = 0.f;
    int cnt = 0;
    if (q == 0) {
        const int t0 = tg[1];
        const int t0w = (t0 < 0) ? t0 + TP2 : t0;
        acc += trans[T_TAGS * TP2 + t0w];
    }
    #pragma unroll
    for (int k = 0; k < CH_LEN; ++k) {
        const int s = s0 + k;
        const int c = tg[k + 1];
        const float m = (c != PAD_I) ? 1.f : 0.f;
        cnt += (c != PAD_I) ? 1 : 0;
        if (s >= 1) {
            const int p  = tg[k];
            const int pw = (p < 0) ? p + TP2 : p;
            const int cw = (c < 0) ? c + TP2 : c;
            acc += trans[pw * TP2 + cw] * m;
        }
        if (s <= S_LEN - 2) {
            int cc = c; if (cc < 0) cc = 0; if (cc > T_TAGS - 1) cc = T_TAGS - 1;
            acc += em[((size_t)s * B_SZ + b) * T_TAGS + cc] * m;
        }
    }
    pl[q * B_SZ + b] = acc;
    pc[q * B_SZ + b] = cnt;
}

// ---------------- Finish: last-step terms + mean(llh - denom) ----------------
__global__ __launch_bounds__(512) void finish_kernel(
    const float* __restrict__ em,
    const float* __restrict__ trans,
    const int*   __restrict__ tags,
    const float* __restrict__ pl, const int* __restrict__ pc,
    const float* __restrict__ denom,
    float* __restrict__ out)
{
    const int b = threadIdx.x;
    float llh = 0.f;
    int cnt = 0;
    #pragma unroll
    for (int q = 0; q < NCHUNK; ++q) {
        llh += pl[q * B_SZ + b];
        cnt += pc[q * B_SZ + b];
    }
    int li = cnt - 1; if (li < 0) li = 0;
    const int lt  = tags[li * B_SZ + b];
    const int ltw = (lt < 0) ? lt + TP2 : lt;
    llh += trans[ltw * TP2 + (T_TAGS + 1)];
    const float ml = (tags[(S_LEN - 1) * B_SZ + b] != PAD_I) ? 1.f : 0.f;
    int ltc = lt; if (ltc < 0) ltc = 0; if (ltc > T_TAGS - 1) ltc = T_TAGS - 1;
    llh += em[((size_t)(S_LEN - 1) * B_SZ + b) * T_TAGS + ltc] * ml;

    float v = llh - denom[b];
    #pragma unroll
    for (int off = 32; off; off >>= 1)
        v += __shfl_xor(v, off);
    __shared__ float sred[8];
    if ((b & 63) == 0) sred[b >> 6] = v;
    __syncthreads();
    if (b == 0) {
        float s = 0.f;
        #pragma unroll
        for (int k = 0; k < 8; ++k) s += sred[k];
        out[0] = s * (1.f / (float)B_SZ);
    }
}

extern "C" void kernel_launch(void* const* d_in, const int* in_sizes, int n_in,
                              void* d_out, int out_size, void* d_ws, size_t ws_size,
                              hipStream_t stream) {
    const float* em    = (const float*)d_in[0];
    const float* trans = (const float*)d_in[1];
    const int*   tags  = (const int*)d_in[2];
    float* out   = (float*)d_out;

    float* denom = (float*)d_ws;                    // 512 f
    float* pl    = denom + B_SZ;                    // 16*512 f
    int*   pc    = (int*)(pl + NCHUNK * B_SZ);      // 16*512 i

    numer_part<<<NCHUNK, B_SZ, 0, stream>>>(em, trans, tags, pl, pc);
    fwd_kernel<<<B_SZ, 512, 0, stream>>>(em, trans, tags, denom);
    finish_kernel<<<1, B_SZ, 0, stream>>>(em, trans, tags, pl, pc, denom, out);
}